// Round 3
// baseline (814.370 us; speedup 1.0000x reference)
//
#include <hip/hip_runtime.h>

#define NDIM  2048
#define WAVES 32
#define BCOLS 2176            // 0..2048 valid + pad
#define SLOTS 2128            // 2112 steps + 16 prefetch overrun
#define ENCB  0x40000000
#define SENTV 0xFFFFFFFFFFFFFFFFull

typedef unsigned long long u64;

// Static scratch: no dependence on ws_size. Prep kernels rewrite everything
// main relies on, every launch (graph-replay safe).
// g_S4[w][sidx][lane] = {exp theta[w*64+lane][sidx-lane][0..2], 0} or zeros when
// col out of range. float4-padded so the per-step read is ONE dwordx4,
// contiguous across lanes (coalesced: 1KB/wave-load).
__device__ __align__(16) float4 g_S4[(size_t)WAVES * SLOTS * 64];
__device__ __align__(16) u64    g_B[(size_t)(WAVES+1) * BCOLS * 2]; // boundary handoff

__device__ __forceinline__ u64 ald(const u64* p) {
  return __hip_atomic_load(p, __ATOMIC_RELAXED, __HIP_MEMORY_SCOPE_AGENT);
}
__device__ __forceinline__ void ast(u64* p, u64 v) {
  __hip_atomic_store(p, v, __ATOMIC_RELAXED, __HIP_MEMORY_SCOPE_AGENT);
}
// shift-up-by-1 across the wave via DPP wave_shr1 (VALU, no LDS latency).
// Lane 0 receives 0 (bound_ctrl old=0) and is overwritten by the boundary select.
__device__ __forceinline__ float shup1(float x) {
  int v = __builtin_amdgcn_update_dpp(0, __float_as_int(x), 0x138, 0xf, 0xf, false);
  return __int_as_float(v);
}

// ---------------- prep A: exp(theta) transposed into staircase order --------
__global__ void vit_prep_theta(const float* __restrict__ theta) {
  const int tid = blockIdx.x * blockDim.x + threadIdx.x;
  const int stride = gridDim.x * blockDim.x;
  const int total = WAVES * SLOTS * 64;
  for (int i = tid; i < total; i += stride) {
    const int l    = i & 63;
    const int rest = i >> 6;
    const int s    = rest % SLOTS;
    const int w    = rest / SLOTS;
    const int row  = w * 64 + l;
    const int col  = s - l;
    float4 r = make_float4(0.f, 0.f, 0.f, 0.f);
    if (col >= 0 && col < NDIM) {
      const float* tp = theta + ((size_t)row * NDIM + col) * 3;
      r.x = __expf(tp[0]); r.y = __expf(tp[1]); r.z = __expf(tp[2]);
    }
    g_S4[i] = r;
  }
}

// ---------------- prep B: sentinel/boundary init ---------------------------
__global__ void vit_prep_bnd() {
  const int tid = blockIdx.x * blockDim.x + threadIdx.x;
  const int stride = gridDim.x * blockDim.x;
  const int nb = (WAVES+1) * BCOLS;
  const u64 hi0 = ((u64)(unsigned)ENCB) << 32;   // (Y=0, e_enc=ENCB i.e. e=0)
  for (int i = tid; i < nb; i += stride) {
    int w = i / BCOLS;
    int c = i - w * BCOLS;
    u64 lo, hi;
    if (c > NDIM)    { lo = 0ull; hi = hi0; }                                   // pad cols: zeros
    else if (w == 0) { lo = (c == 0) ? (u64)__float_as_uint(1.0f) : 0ull; hi = hi0; } // row 0
    else if (c == 0) { lo = 0ull; hi = hi0; }                                   // V[i,0] = -inf
    else             { lo = SENTV; hi = SENTV; }                                // to be produced
    ast(&g_B[(size_t)i*2],   lo);
    ast(&g_B[(size_t)i*2+1], hi);
  }
}

// ---------------- main: 32 waves, striped wavefront, exp-space -------------
// The 16-step inner body is expanded with LITERAL step indices (STEP(0..15))
// so every ring access is compile-time-indexed -> SROA -> registers.
// (Round-2 evidence: VGPR_Count=72 < the ~130 the rings need => the pragma
// unroll version left the rings in scratch; every consume then waited on the
// just-issued theta prefetch through in-order vmcnt => ~410 cyc/step.)
__global__ void __launch_bounds__(64, 1) vit_main(const float* __restrict__ A,
                                                  float* __restrict__ out) {
  const int lane = threadIdx.x;
  const int w    = blockIdx.x;
  const bool isL0 = (lane == 0);

  const float a00 = __expf(A[0]), a01 = __expf(A[1]), a02 = __expf(A[2]);
  const float a10 = __expf(A[3]), a11 = __expf(A[4]), a12 = __expf(A[5]);
  const float a20 = __expf(A[6]), a21 = __expf(A[7]), a22 = __expf(A[8]);

  const float4* tb4 = g_S4 + (size_t)w * SLOTS * 64 + lane;
  u64* bin  = g_B + (size_t)w     * BCOLS * 2;
  u64* bout = g_B + (size_t)(w+1) * BCOLS * 2;

  // state: own row col j-1 (p), row-above col j (u), row-above col j-1 (ud)
  float Mp=0.f,Xp=0.f,Yp=0.f, Mu=0.f,Xu=0.f,Yu=0.f, Mud=0.f,Xud=0.f,Yud=0.f;
  int e_w = 0;  // wave scale: registers hold value * 2^-e_w

  // theta prefetch ring (distance 16): slot u holds sidx = base+u (for s=base+u+1)
  float4 tq[16];
  #pragma unroll
  for (int u = 0; u < 16; ++u) tq[u] = tb4[(size_t)u * 64];

  // boundary prefetch ring (distance 8): cols 2..9 at slot (col&7)
  u64 rLo[8], rHi[8];
  #pragma unroll
  for (int c = 2; c <= 9; ++c) {
    rLo[c & 7] = ald(bin + (size_t)c*2);
    rHi[c & 7] = ald(bin + (size_t)c*2 + 1);
  }
  // col 0 -> ud (prefilled, never sentinel)
  {
    u64 lo = ald(bin), hi = ald(bin + 1);
    while (lo == SENTV || hi == SENTV) { __builtin_amdgcn_s_sleep(2); lo = ald(bin); hi = ald(bin+1); }
    if (isL0) {
      Mud = __uint_as_float((unsigned)lo);
      Xud = __uint_as_float((unsigned)(lo >> 32));
      Yud = __uint_as_float((unsigned)hi);
    }
  }
  // col 1 -> u (spin = pipeline fill)
  {
    u64 lo = ald(bin + 2), hi = ald(bin + 3);
    while (lo == SENTV || hi == SENTV) { __builtin_amdgcn_s_sleep(8); lo = ald(bin+2); hi = ald(bin+3); }
    int ep = (int)((unsigned)(hi >> 32) - (unsigned)ENCB);
    int dd = ep - e_w;
    if (__builtin_amdgcn_readfirstlane(dd) > 48) { e_w = ep; dd = 0; } // states are zero
    if (isL0) {
      Mu = ldexpf(__uint_as_float((unsigned)lo), dd);
      Xu = ldexpf(__uint_as_float((unsigned)(lo >> 32)), dd);
      Yu = ldexpf(__uint_as_float((unsigned)hi), dd);
    }
  }

#define STEP(U)                                                                \
  {                                                                            \
    const int s = base + (U) + 1;           /* lane computes col j = s-lane */ \
    const float T0 = tq[U].x, T1 = tq[U].y, T2 = tq[U].z;                      \
    float mn = T0 * fmaf(a02, Yud, fmaf(a01, Xud, a00*Mud));                   \
    float xn = T1 * fmaf(a12, Yu,  fmaf(a11, Xu,  a10*Mu));                    \
    float yn = T2 * fmaf(a22, Yp,  fmaf(a21, Xp,  a20*Mp));                    \
    /* producer handoff (lane 63 = wave's last row) */                         \
    if (s >= 64 && lane == 63) {                                               \
      u64 slo = ((u64)__float_as_uint(xn) << 32) | __float_as_uint(mn);        \
      u64 shi = ((u64)(unsigned)(e_w + ENCB) << 32) | __float_as_uint(yn);     \
      ast(bO + (size_t)(U)*2,     slo);                                        \
      ast(bO + (size_t)(U)*2 + 1, shi);                                        \
    }                                                                          \
    /* terminal: V[2048,2048] at wave 31, lane 63, s = 2111 */                 \
    if (s == 2111 && w == 31 && lane == 63) {                                  \
      out[0] = (log2f(mn + xn + yn) + (float)e_w) * 0.69314718055994531f;      \
    }                                                                          \
    /* theta prefetch for s+16 (coalesced dwordx4) */                          \
    tq[U] = tA4[(size_t)(U) * 64];                                             \
    /* boundary consume for col s+1 (slot (U+2)&7) */                          \
    u64 lo = rLo[((U)+2)&7], hi = rHi[((U)+2)&7];                              \
    if (lo == SENTV || hi == SENTV) {                                          \
      lo = ald(bS + (size_t)(U)*2); hi = ald(bS + (size_t)(U)*2 + 1);          \
      while (lo == SENTV || hi == SENTV) {                                     \
        __builtin_amdgcn_s_sleep(2);                                           \
        lo = ald(bS + (size_t)(U)*2); hi = ald(bS + (size_t)(U)*2 + 1);        \
      }                                                                        \
    }                                                                          \
    const float Mb = __uint_as_float((unsigned)lo);                            \
    const float Xb = __uint_as_float((unsigned)(lo >> 32));                    \
    const float Yb = __uint_as_float((unsigned)hi);                            \
    int d = (int)((unsigned)(hi >> 32) - (unsigned)ENCB) - e_w;                \
    if (__builtin_amdgcn_readfirstlane(d) > 48) {                              \
      /* producer's magnitude dwarfs ours: adopt its scale */                  \
      const int ep = (int)((unsigned)(hi >> 32) - (unsigned)ENCB);             \
      const int sh = e_w - ep;                                                 \
      mn = ldexpf(mn,sh); xn = ldexpf(xn,sh); yn = ldexpf(yn,sh);              \
      Mu = ldexpf(Mu,sh); Xu = ldexpf(Xu,sh); Yu = ldexpf(Yu,sh);              \
      Mud= ldexpf(Mud,sh);Xud= ldexpf(Xud,sh);Yud= ldexpf(Yud,sh);             \
      e_w = ep; d = 0;                                                         \
    }                                                                          \
    /* boundary prefetch col s+9 into the slot just consumed */                \
    rLo[((U)+2)&7] = ald(bA + (size_t)(U)*2);                                  \
    rHi[((U)+2)&7] = ald(bA + (size_t)(U)*2 + 1);                              \
    /* rotate */                                                               \
    Mud = Mu; Xud = Xu; Yud = Yu;                                              \
    const float sm = shup1(mn);                                                \
    const float sx = shup1(xn);                                                \
    const float sy = shup1(yn);                                                \
    Mu = isL0 ? ldexpf(Mb, d) : sm;                                            \
    Xu = isL0 ? ldexpf(Xb, d) : sx;                                            \
    Yu = isL0 ? ldexpf(Yb, d) : sy;                                            \
    Mp = mn; Xp = xn; Yp = yn;                                                 \
  }

  for (int base = 0; base < 2112; base += 16) {
    const float4* tA4 = tb4 + (size_t)(base + 16) * 64;    // theta prefetch for s+16
    u64* bA = bin + (size_t)(base + 10)*2;                 // prefetch col s+9
    u64* bS = bin + (size_t)(base + 2)*2;                  // spin reload col s+1
    u64* bO = bout + (size_t)(base - 62)*2;                // store col s-63
    STEP(0)  STEP(1)  STEP(2)  STEP(3)
    STEP(4)  STEP(5)  STEP(6)  STEP(7)
    STEP(8)  STEP(9)  STEP(10) STEP(11)
    STEP(12) STEP(13) STEP(14) STEP(15)
    // epoch rescale (wave-uniform, exact power-of-2)
    {
      float m = fmaxf(fmaxf(Mp, Xp), Yp);
      const int jl = base + 16 - lane;          // last computed column
      if (jl < 1 || jl > NDIM) m = 0.0f;        // exclude warmup/drain junk lanes
      #pragma unroll
      for (int off = 1; off < 64; off <<= 1) m = fmaxf(m, __shfl_xor(m, off));
      int E = (int)((__float_as_uint(m) >> 23) & 0xFF) - 127;
      if (m == 0.0f) E = 0;
      const int sh = -E;
      Mp = ldexpf(Mp,sh); Xp = ldexpf(Xp,sh); Yp = ldexpf(Yp,sh);
      Mu = ldexpf(Mu,sh); Xu = ldexpf(Xu,sh); Yu = ldexpf(Yu,sh);
      Mud= ldexpf(Mud,sh);Xud= ldexpf(Xud,sh);Yud= ldexpf(Yud,sh);
      e_w += E;
    }
  }
#undef STEP
}

extern "C" void kernel_launch(void* const* d_in, const int* in_sizes, int n_in,
                              void* d_out, int out_size, void* d_ws, size_t ws_size,
                              hipStream_t stream) {
  const float* theta = (const float*)d_in[0];
  const float* A     = (const float*)d_in[1];
  float* out = (float*)d_out;
  (void)in_sizes; (void)n_in; (void)out_size; (void)d_ws; (void)ws_size;
  vit_prep_theta<<<dim3(8192), dim3(256), 0, stream>>>(theta);
  vit_prep_bnd<<<dim3(256), dim3(256), 0, stream>>>();
  vit_main<<<dim3(WAVES), dim3(64), 0, stream>>>(A, out);
}

// Round 4
// 780.503 us; speedup vs baseline: 1.0434x; 1.0434x over previous
//
#include <hip/hip_runtime.h>

#define NDIM  2048
#define WAVES 32
#define BCOLS 2176            // 0..2048 valid + pad
#define SLOTS 2128            // 2112 steps + 16 prefetch overrun
#define ENCB  0x40000000
#define SENTV 0xFFFFFFFFFFFFFFFFull

typedef unsigned long long u64;

// Static scratch: prep kernels rewrite everything main relies on, every launch.
// g_S4[w][sidx][lane] = {exp theta[w*64+lane][sidx-lane][0..2], 0}; float4 so the
// per-slot read is ONE coalesced dwordx4 (1KB/wave).
__device__ __align__(16) float4 g_S4[(size_t)WAVES * SLOTS * 64];
__device__ __align__(16) u64    g_B[(size_t)(WAVES+1) * BCOLS * 2]; // boundary handoff

__device__ __forceinline__ u64 ald(const u64* p) {
  return __hip_atomic_load(p, __ATOMIC_RELAXED, __HIP_MEMORY_SCOPE_AGENT);
}
__device__ __forceinline__ void ast(u64* p, u64 v) {
  __hip_atomic_store(p, v, __ATOMIC_RELAXED, __HIP_MEMORY_SCOPE_AGENT);
}
// shift-up-by-1 across the wave via DPP wave_shr1. Lane 0 receives 0 and is
// overwritten by the boundary select.
__device__ __forceinline__ float shup1(float x) {
  int v = __builtin_amdgcn_update_dpp(0, __float_as_int(x), 0x138, 0xf, 0xf, false);
  return __int_as_float(v);
}

// ---------------- prep A: exp(theta) transposed into staircase order --------
__global__ void vit_prep_theta(const float* __restrict__ theta) {
  const int tid = blockIdx.x * blockDim.x + threadIdx.x;
  const int stride = gridDim.x * blockDim.x;
  const int total = WAVES * SLOTS * 64;
  for (int i = tid; i < total; i += stride) {
    const int l    = i & 63;
    const int rest = i >> 6;
    const int s    = rest % SLOTS;
    const int w    = rest / SLOTS;
    const int row  = w * 64 + l;
    const int col  = s - l;
    float4 r = make_float4(0.f, 0.f, 0.f, 0.f);
    if (col >= 0 && col < NDIM) {
      const float* tp = theta + ((size_t)row * NDIM + col) * 3;
      r.x = __expf(tp[0]); r.y = __expf(tp[1]); r.z = __expf(tp[2]);
    }
    g_S4[i] = r;
  }
}

// ---------------- prep B: sentinel/boundary init ---------------------------
__global__ void vit_prep_bnd() {
  const int tid = blockIdx.x * blockDim.x + threadIdx.x;
  const int stride = gridDim.x * blockDim.x;
  const int nb = (WAVES+1) * BCOLS;
  const u64 hi0 = ((u64)(unsigned)ENCB) << 32;   // (Y=0, e=0)
  for (int i = tid; i < nb; i += stride) {
    int w = i / BCOLS;
    int c = i - w * BCOLS;
    u64 lo, hi;
    if (c > NDIM)    { lo = 0ull; hi = hi0; }                                   // pad cols
    else if (w == 0) { lo = (c == 0) ? (u64)__float_as_uint(1.0f) : 0ull; hi = hi0; } // row 0
    else if (c == 0) { lo = 0ull; hi = hi0; }                                   // V[i,0] = -inf
    else             { lo = SENTV; hi = SENTV; }                                // to be produced
    ast(&g_B[(size_t)i*2],   lo);
    ast(&g_B[(size_t)i*2+1], hi);
  }
}

// ---------------- main: 32 waves, striped wavefront, exp-space -------------
// Structure per 16-step block:
//   [validate]  ring regs for THIS block (one __ballot spin; the only loads-in-
//               loop construct -> the one conservative vmcnt(0) per block lands
//               on 16-step-old loads = free)
//   [stage]     16 theta dwordx4 (regs, for block k+1) + 1 striped boundary
//               group load (lane u holds col C+u) ; sched_barrier pins them here
//   [steps 0..15] pure VALU + readlane consumes + exec-masked handoff stores.
//               No loads, no spins -> waitcnt state stays exact.
__global__ void __launch_bounds__(64, 1)
__attribute__((amdgpu_waves_per_eu(1, 1)))
vit_main(const float* __restrict__ A, float* __restrict__ out) {
  const int lane = threadIdx.x;
  const int w    = blockIdx.x;
  const bool isL0 = (lane == 0);
  const int lsel = lane & 15;

  const float a00 = __expf(A[0]), a01 = __expf(A[1]), a02 = __expf(A[2]);
  const float a10 = __expf(A[3]), a11 = __expf(A[4]), a12 = __expf(A[5]);
  const float a20 = __expf(A[6]), a21 = __expf(A[7]), a22 = __expf(A[8]);

  const float4* tb4 = g_S4 + (size_t)w * SLOTS * 64 + lane;
  u64* bin  = g_B + (size_t)w     * BCOLS * 2;
  u64* bout = g_B + (size_t)(w+1) * BCOLS * 2;

  // state: own row col j-1 (p), row-above col j (u), row-above col j-1 (ud)
  float Mp=0.f,Xp=0.f,Yp=0.f, Mu=0.f,Xu=0.f,Yu=0.f, Mud=0.f,Xud=0.f,Yud=0.f;
  int e_w = 0;   // wave scale: registers hold value * 2^-e_w
  int se_w = 0;  // scalar copy, refreshed each block

  // ---- theta block 0 (slots 0..15) into named regs ----
  float4 Ta0  = tb4[0*64],  Ta1  = tb4[1*64],  Ta2  = tb4[2*64],  Ta3  = tb4[3*64];
  float4 Ta4  = tb4[4*64],  Ta5  = tb4[5*64],  Ta6  = tb4[6*64],  Ta7  = tb4[7*64];
  float4 Ta8  = tb4[8*64],  Ta9  = tb4[9*64],  Ta10 = tb4[10*64], Ta11 = tb4[11*64];
  float4 Ta12 = tb4[12*64], Ta13 = tb4[13*64], Ta14 = tb4[14*64], Ta15 = tb4[15*64];
  float4 Tb0  = make_float4(0,0,0,0), Tb1  = Tb0, Tb2  = Tb0, Tb3  = Tb0;
  float4 Tb4  = Tb0, Tb5  = Tb0, Tb6  = Tb0, Tb7  = Tb0;
  float4 Tb8  = Tb0, Tb9  = Tb0, Tb10 = Tb0, Tb11 = Tb0;
  float4 Tb12 = Tb0, Tb13 = Tb0, Tb14 = Tb0, Tb15 = Tb0;

  // ---- boundary ring: lane-striped. Block k group = cols k*16+2 .. k*16+17,
  //      lane u (u=lsel) holds col k*16+2+u. Preload block 0; rpn -> block 1. ----
  u64 cLoa, cHia, cLob = 0, cHib = 0;
  u64* rpn;
  {
    u64* rp0 = bin + (size_t)(2 + lsel) * 2;
    cLoa = ald(rp0); cHia = ald(rp0 + 1);
    rpn = rp0 + 32;
  }

  // col 0 -> ud (prefilled, never sentinel)
  {
    u64 lo = ald(bin), hi = ald(bin + 1);
    while (lo == SENTV || hi == SENTV) { __builtin_amdgcn_s_sleep(2); lo = ald(bin); hi = ald(bin+1); }
    if (isL0) {
      Mud = __uint_as_float((unsigned)lo);
      Xud = __uint_as_float((unsigned)(lo >> 32));
      Yud = __uint_as_float((unsigned)hi);
    }
  }
  // col 1 -> u (spin = pipeline fill)
  {
    u64 lo = ald(bin + 2), hi = ald(bin + 3);
    while (lo == SENTV || hi == SENTV) { __builtin_amdgcn_s_sleep(8); lo = ald(bin+2); hi = ald(bin+3); }
    int ep = (int)((unsigned)(hi >> 32) - (unsigned)ENCB);
    int dd = ep - e_w;
    if (__builtin_amdgcn_readfirstlane(dd) > 48) { e_w = ep; dd = 0; } // states are zero
    if (isL0) {
      Mu = ldexpf(__uint_as_float((unsigned)lo), dd);
      Xu = ldexpf(__uint_as_float((unsigned)(lo >> 32)), dd);
      Yu = ldexpf(__uint_as_float((unsigned)hi), dd);
    }
  }

#define STEP(U, S)                                                             \
  {                                                                            \
    const int s = base + (U) + 1;           /* lane computes col j = s-lane */ \
    const float T0v = T##S##U.x, T1v = T##S##U.y, T2v = T##S##U.z;             \
    float mn = T0v * fmaf(a02, Yud, fmaf(a01, Xud, a00*Mud));                  \
    float xn = T1v * fmaf(a12, Yu,  fmaf(a11, Xu,  a10*Mu));                   \
    float yn = T2v * fmaf(a22, Yp,  fmaf(a21, Xp,  a20*Mp));                   \
    /* producer handoff (lane 63 = wave's last row) */                         \
    if (s >= 64 && lane == 63) {                                               \
      u64 slo = ((u64)__float_as_uint(xn) << 32) | __float_as_uint(mn);        \
      u64 shi = ((u64)(unsigned)(e_w + ENCB) << 32) | __float_as_uint(yn);     \
      ast(bO + (size_t)(U)*2,     slo);                                        \
      ast(bO + (size_t)(U)*2 + 1, shi);                                        \
    }                                                                          \
    /* terminal: V[2048,2048] at wave 31, lane 63, s = 2111 */                 \
    if (s == 2111 && w == 31 && lane == 63) {                                  \
      out[0] = (log2f(mn + xn + yn) + (float)e_w) * 0.69314718055994531f;      \
    }                                                                          \
    /* boundary consume for col s+1: lane (U) of striped ring -> scalar */     \
    const int Mbb = __builtin_amdgcn_readlane((int)(unsigned)(cLo##S), (U));   \
    const int Xbb = __builtin_amdgcn_readlane((int)(unsigned)((cLo##S)>>32), (U)); \
    const int Ybb = __builtin_amdgcn_readlane((int)(unsigned)(cHi##S), (U));   \
    const int Ebb = __builtin_amdgcn_readlane((int)(unsigned)((cHi##S)>>32), (U)); \
    int ds = (Ebb - ENCB) - se_w;                                              \
    if (ds > 48) {                                                             \
      /* producer's magnitude dwarfs ours: adopt its scale */                  \
      const int ep = Ebb - ENCB;                                               \
      const int sh = se_w - ep;                                                \
      mn = ldexpf(mn,sh); xn = ldexpf(xn,sh); yn = ldexpf(yn,sh);              \
      Mu = ldexpf(Mu,sh); Xu = ldexpf(Xu,sh); Yu = ldexpf(Yu,sh);              \
      Mud= ldexpf(Mud,sh);Xud= ldexpf(Xud,sh);Yud= ldexpf(Yud,sh);             \
      e_w = ep; se_w = ep; ds = 0;                                             \
    }                                                                          \
    /* rotate */                                                               \
    Mud = Mu; Xud = Xu; Yud = Yu;                                              \
    const float sm = shup1(mn);                                                \
    const float sx = shup1(xn);                                                \
    const float sy = shup1(yn);                                                \
    Mu = isL0 ? ldexpf(__int_as_float(Mbb), ds) : sm;                          \
    Xu = isL0 ? ldexpf(__int_as_float(Xbb), ds) : sx;                          \
    Yu = isL0 ? ldexpf(__int_as_float(Ybb), ds) : sy;                          \
    Mp = mn; Xp = xn; Yp = yn;                                                 \
  }

#define BLOCK(S, SN)                                                           \
  {                                                                            \
    /* ---- validate ring S (cols base+2 .. base+17, striped) ---- */          \
    u64* rpc_ = rpn - 32;                                                      \
    bool bad_ = (cLo##S == SENTV) || (cHi##S == SENTV);                        \
    while (__ballot(bad_)) {                                                   \
      __builtin_amdgcn_s_sleep(1);                                             \
      cLo##S = ald(rpc_); cHi##S = ald(rpc_ + 1);                              \
      bad_ = (cLo##S == SENTV) || (cHi##S == SENTV);                           \
    }                                                                          \
    se_w = __builtin_amdgcn_readfirstlane(e_w);                                \
    /* ---- stage block k+1: theta regs + striped boundary group ---- */       \
    {                                                                          \
      const float4* tn_ = tb4 + (size_t)(base + 16) * 64;                      \
      T##SN##0  = tn_[0*64];  T##SN##1  = tn_[1*64];                           \
      T##SN##2  = tn_[2*64];  T##SN##3  = tn_[3*64];                           \
      T##SN##4  = tn_[4*64];  T##SN##5  = tn_[5*64];                           \
      T##SN##6  = tn_[6*64];  T##SN##7  = tn_[7*64];                           \
      T##SN##8  = tn_[8*64];  T##SN##9  = tn_[9*64];                           \
      T##SN##10 = tn_[10*64]; T##SN##11 = tn_[11*64];                          \
      T##SN##12 = tn_[12*64]; T##SN##13 = tn_[13*64];                          \
      T##SN##14 = tn_[14*64]; T##SN##15 = tn_[15*64];                          \
    }                                                                          \
    cLo##SN = ald(rpn); cHi##SN = ald(rpn + 1);                                \
    rpn += 32;                                                                 \
    __builtin_amdgcn_sched_barrier(0);                                         \
    /* ---- 16 pure-compute steps ---- */                                      \
    u64* bO = bout + (size_t)(base - 62) * 2;                                  \
    STEP(0,S)  STEP(1,S)  STEP(2,S)  STEP(3,S)                                 \
    STEP(4,S)  STEP(5,S)  STEP(6,S)  STEP(7,S)                                 \
    STEP(8,S)  STEP(9,S)  STEP(10,S) STEP(11,S)                                \
    STEP(12,S) STEP(13,S) STEP(14,S) STEP(15,S)                                \
    /* ---- epoch rescale (wave-uniform, exact power-of-2) ---- */             \
    {                                                                          \
      float m = fmaxf(fmaxf(Mp, Xp), Yp);                                      \
      const int jl = base + 16 - lane;                                         \
      if (jl < 1 || jl > NDIM) m = 0.0f;                                       \
      m = fmaxf(m, __shfl_xor(m, 1));                                          \
      m = fmaxf(m, __shfl_xor(m, 2));                                          \
      m = fmaxf(m, __shfl_xor(m, 4));                                          \
      m = fmaxf(m, __shfl_xor(m, 8));                                          \
      m = fmaxf(m, __shfl_xor(m, 16));                                         \
      m = fmaxf(m, __shfl_xor(m, 32));                                         \
      int E = (int)((__float_as_uint(m) >> 23) & 0xFF) - 127;                  \
      if (m == 0.0f) E = 0;                                                    \
      const int sh = -E;                                                       \
      Mp = ldexpf(Mp,sh); Xp = ldexpf(Xp,sh); Yp = ldexpf(Yp,sh);              \
      Mu = ldexpf(Mu,sh); Xu = ldexpf(Xu,sh); Yu = ldexpf(Yu,sh);              \
      Mud= ldexpf(Mud,sh);Xud= ldexpf(Xud,sh);Yud= ldexpf(Yud,sh);             \
      e_w += E;                                                                \
    }                                                                          \
    base += 16;                                                                \
  }

  int base = 0;
  for (int it = 0; it < 66; ++it) {   // 132 blocks of 16 steps = 2112
    BLOCK(a, b)
    BLOCK(b, a)
  }
#undef BLOCK
#undef STEP
}

extern "C" void kernel_launch(void* const* d_in, const int* in_sizes, int n_in,
                              void* d_out, int out_size, void* d_ws, size_t ws_size,
                              hipStream_t stream) {
  const float* theta = (const float*)d_in[0];
  const float* A     = (const float*)d_in[1];
  float* out = (float*)d_out;
  (void)in_sizes; (void)n_in; (void)out_size; (void)d_ws; (void)ws_size;
  vit_prep_theta<<<dim3(8192), dim3(256), 0, stream>>>(theta);
  vit_prep_bnd<<<dim3(256), dim3(256), 0, stream>>>();
  vit_main<<<dim3(WAVES), dim3(64), 0, stream>>>(A, out);
}